// Round 9
// baseline (241.649 us; speedup 1.0000x reference)
//
#include <hip/hip_runtime.h>
#include <math.h>

#define HH 1024
#define WW 1024
#define OUTW 58            // output columns per wave (64 lanes - 6 halo)
#define RPB 4              // output rows per WAVE (vertical slide length)
#define WPB 4              // waves per block (independent y-strips, no barrier)
#define OFF(i) ((i)*8 - (i)*((i)-1)/2)   // packed upper-tri row offset

// ===== R25: hybrid VALU/DS htap — offload taps to the idle DS pipe =====
// Hard-won constraints (rounds 4..24):
//  - VGPR bucket MUST stay 128. WRITE_SIZE == 13536 KB is the no-spill
//    invariant (violations: r7/r16/r17/r18).
//  - Theories refuted: TLP up/down (r13/r10/R22/R23), VMEM latency
//    (R20 prefetch = only -5%), block concurrency (R23), HBM traffic
//    (FETCH anti-correlates with dur), solve-bubble ILP (R24).
//  - Surviving law: VALUBusy x dur ~= 25-28 us across ALL rounds;
//    VALUBusy pinned 42-50% over occupancy 4.4-7.7 waves/CU.
//    => reduce VALU instructions or move them to another pipe.
//  - Cross-lane ops only in all-lane (non-divergent) context (r8).
//  - No LDS prefetch: s_waitcnt vmcnt(0) drains output stores (r15).
// R25 change vs R21 (base kept verbatim otherwise):
//  - htap12 inner: depth-6 pure-DPP chain (6 VALU) -> depth-4 tree
//    (4 VALU + 3 ds_bpermute on the idle DS pipe):
//      a = x + wshr1(x)            {L-1..L}
//      b = a + bperm(a, L-2)       {L-3..L}
//      d1= bperm(a,L-4)+bperm(x,L-6) {L-6..L-4}
//      dst = b + d1                {L-6..L}
//    Taps/iter: 360 VALU -> 240 VALU + 180 DS. Lanes 0-5 get wrapped
//    bpermute garbage - never stored (same as pre-R19 champion).
//  - Discriminator: dur down => VALU-pipe-bound (pack fp32 next);
//    dur up => issue-slot-bound (minimize raw inst count next).

// DPP move, bound_ctrl=1 (invalid lanes read 0)
template<int CTRL>
__device__ __forceinline__ float dpp0(float x) {
    return __int_as_float(
        __builtin_amdgcn_update_dpp(0, __float_as_int(x), CTRL, 0xf, 0xf, true));
}
// whole-wave shift right by 1 lane (crosses 16-lane row boundaries)
__device__ __forceinline__ float wshr1(float x) { return dpp0<0x138>(x); }

// fp32 reciprocal: v_rcp_f32 + 1 Newton step (~1ulp); LDL^T is sqrt-free
__device__ __forceinline__ float frcp_fast(float s) {
    float r = __builtin_amdgcn_rcpf(s);
    return r * fmaf(-s, r, 2.0f);
}

static_assert(RPB == 4, "iteration schedule below is hand-unrolled for RPB=4");

__global__ __launch_bounds__(WPB * 64, 2) void ls_sep_kernel(
    const float* __restrict__ inp,    // [3,H,W]
    const float* __restrict__ dep,    // [1,H,W]
    const float* __restrict__ alb,    // [3,H,W]
    const float* __restrict__ nrm,    // [3,H,W]
    float* __restrict__ out)          // [3,H,W]
{
    const int L  = threadIdx.x & 63;          // lane 0..63
    const int wv = threadIdx.x >> 6;          // wave 0..3 (independent y-strip)
    const int HW = HH * WW;
    // lane L sums column x; its horizontal window (x-6..x) is centered at x-3
    const int x  = OUTW * blockIdx.x - 3 + L;
    const int y0 = (RPB * WPB) * blockIdx.y + RPB * wv;
    const int px = x - 3;                     // output pixel column for this lane

    const int xc    = min(max(x, 0), WW - 1);
    const float xok = (x >= 0 && x < WW) ? 1.f : 0.f;

    // per-channel SGPR base pointers (one s-pair each; loads share voffset)
    const float* __restrict__ d0 = dep;
    const float* __restrict__ a0 = alb;
    const float* __restrict__ a1 = alb + HW;
    const float* __restrict__ a2 = alb + 2 * HW;
    const float* __restrict__ n0 = nrm;
    const float* __restrict__ n1 = nrm + HW;
    const float* __restrict__ n2 = nrm + 2 * HW;
    const float* __restrict__ i0 = inp;
    const float* __restrict__ i1 = inp + HW;
    const float* __restrict__ i2 = inp + 2 * HW;
    float* __restrict__ o0 = out;
    float* __restrict__ o1 = out + HW;
    float* __restrict__ o2 = out + 2 * HW;

    float C[60];                              // running column sums (7 rows in y)
    #pragma unroll
    for (int k = 0; k < 60; k++) C[k] = 0.f;

    // clamped-address loads only; no C update (prefetchable)
    auto load_row = [&](int yy, float (&fv)[8], float (&yv)[3]) {
        const int yc = min(max(yy, 0), HH - 1);
        const int p = yc * WW + xc;
        fv[0] = 1.f;
        fv[1] = d0[p];
        fv[2] = a0[p];
        fv[3] = a1[p];
        fv[4] = a2[p];
        fv[5] = n0[p];
        fv[6] = n1[p];
        fv[7] = n2[p];
        yv[0] = i0[p];
        yv[1] = i1[p];
        yv[2] = i2[p];
    };

    // masked accumulate of a loaded row into the column sums
    auto apply_row = [&](const float (&fv)[8], const float (&yv)[3],
                         int yy, float sgn) {
        const float ok = (yy >= 0 && yy < HH) ? xok : 0.f;
        const float s = sgn * ok;
        float fs[8];
        #pragma unroll
        for (int i = 0; i < 8; i++) fs[i] = fv[i] * s;
        int k = 0;
        #pragma unroll
        for (int i = 0; i < 8; i++)
            #pragma unroll
            for (int j = i; j < 8; j++) { C[k] = fmaf(fs[i], fv[j], C[k]); k++; }
        #pragma unroll
        for (int i = 0; i < 8; i++)
            #pragma unroll
            for (int c = 0; c < 3; c++)
                C[36 + i * 3 + c] = fmaf(fs[i], yv[c], C[36 + i * 3 + c]);
    };

    // prologue: fill the depth-2 add-row pipeline
    float A0f[8], A0y[3], A1f[8], A1y[3];
    load_row(y0 + 3, A0f, A0y);
    load_row(y0 + 4, A1f, A1y);

    // preload rows y0-3 .. y0+2 (iter y0 skips the subtract)
    #pragma unroll 2
    for (int yy = y0 - 3; yy < y0 + 3; yy++) {
        float fv[8], yv[3];
        load_row(yy, fv, yv);
        apply_row(fv, yv, yy, 1.f);
    }

    float Sf[8], Sy[3];                       // sub-row buffer (depth 1)

    const int pxc = min(max(px, 0), WW - 1);
    const bool do_store = (L >= 6) && (px < WW);

    // bpermute byte indices for lanes L-2 / L-4 / L-6 (wrap only for
    // halo lanes 0..5, whose results are never stored)
    const int ixm2 = ((L - 2) & 63) << 2;
    const int ixm4 = ((L - 4) & 63) << 2;
    const int ixm6 = ((L - 6) & 63) << 2;

    // Batched horizontal 7-tap over lanes L-6..L for 12 values at once.
    // Depth-4 tree: 4 VALU + 3 DS-pipe bpermutes per value.
    // MUST be called by all 64 lanes (cross-lane inside).
    auto htap12 = [&](int base, float* dst) {
        #pragma unroll
        for (int j = 0; j < 12; j++) {
            const float xv = C[base + j];
            const float a  = xv + wshr1(xv);                  // {L-1..L}
            const int   ai = __float_as_int(a);
            const float b  = a + __int_as_float(
                __builtin_amdgcn_ds_bpermute(ixm2, ai));      // {L-3..L}
            const float d1 = __int_as_float(
                __builtin_amdgcn_ds_bpermute(ixm4, ai))       // {L-5,L-4}
                           + __int_as_float(
                __builtin_amdgcn_ds_bpermute(ixm6, __float_as_int(xv))); // {L-6}
            dst[j] = b + d1;                                  // {L-6..L}
        }
    };

    // one output row; Af/Ay is the add-row buffer holding row y+3.
    // loadA: refill Af with row y+5 (consumed 2 iters later).
    // loadS: refill Sf with row y-3 (consumed next iter).
    auto iter = [&](int y, float (&Af)[8], float (&Ay)[3],
                    bool first, bool loadA, bool loadS) {
        // ---- consume prefetched rows ----
        apply_row(Af, Ay, y + 3, 1.f);
        if (!first) apply_row(Sf, Sy, y - 4, -1.f);

        // ---- issue loads in consumption order: cf -> S -> A ----
        const int pc = y * WW + pxc;          // center features (this iter)
        float cf[8];
        cf[0] = 1.f;
        cf[1] = d0[pc];
        cf[2] = a0[pc]; cf[3] = a1[pc]; cf[4] = a2[pc];
        cf[5] = n0[pc]; cf[6] = n1[pc]; cf[7] = n2[pc];

        if (loadS) load_row(y - 3, Sf, Sy);   // next iter's sub-row
        if (loadA) load_row(y + 5, Af, Ay);   // iter+2's add-row

        // ---- horizontal taps for AtA (AtY deferred past the solve) ----
        float W[36];
        htap12(0,  &W[0]);
        htap12(12, &W[12]);
        htap12(24, &W[24]);
        #pragma unroll
        for (int i = 0; i < 8; i++) W[OFF(i)] += 1.0e-4f;

        // ---- fp32 LDL^T (sqrt-free). W row i keeps R_ij = d_i*U_ij ----
        float idv[8];
        #pragma unroll
        for (int i = 0; i < 8; i++) {
            #pragma unroll
            for (int k = 0; k < i; k++) {
                const float c = W[OFF(k) + i - k] * idv[k];   // U_ki
                #pragma unroll
                for (int j = i; j < 8; j++)
                    W[OFF(i) + j - i] = fmaf(-c, W[OFF(k) + j - k], W[OFF(i) + j - i]);
            }
            idv[i] = frcp_fast(W[OFF(i)]);    // 1/d_i
        }

        // forward: vt_i = idv_i * (cf_i - sum_{k<i} R_ki * vt_k)
        float vt[8];
        #pragma unroll
        for (int i = 0; i < 8; i++) {
            float s = cf[i];
            #pragma unroll
            for (int k = 0; k < i; k++)
                s = fmaf(-W[OFF(k) + i - k], vt[k], s);
            vt[i] = s * idv[i];
        }
        // back: w_i = vt_i - idv_i * sum_{j>i} R_ij * w_j
        float w[8];
        #pragma unroll
        for (int i = 7; i >= 0; i--) {
            float t = 0.f;
            #pragma unroll
            for (int j = i + 1; j < 8; j++)
                t = fmaf(W[OFF(i) + j - i], w[j], t);
            w[i] = fmaf(-idv[i], t, vt[i]);
        }

        // ---- deferred AtY taps (batched) + output dot products:
        //      ALL lanes execute; only the store is predicated ----
        float r[3] = {0.f, 0.f, 0.f};
        {
            float SY[12];
            htap12(36, SY);                   // AtY for i=0..3
            #pragma unroll
            for (int i = 0; i < 4; i++)
                #pragma unroll
                for (int c = 0; c < 3; c++)
                    r[c] = fmaf(w[i], SY[i * 3 + c], r[c]);
            htap12(48, SY);                   // AtY for i=4..7
            #pragma unroll
            for (int i = 0; i < 4; i++)
                #pragma unroll
                for (int c = 0; c < 3; c++)
                    r[c] = fmaf(w[i + 4], SY[i * 3 + c], r[c]);
        }

        if (do_store) {
            const int p = y * WW + px;
            o0[p] = r[0];
            o1[p] = r[1];
            o2[p] = r[2];
        }
    };

    // hand-unrolled schedule (RPB=4): minimal loads, static buffers
    iter(y0,     A0f, A0y, true,  true,  true);   // A0<-y0+5, S<-y0-3
    iter(y0 + 1, A1f, A1y, false, true,  true);   // A1<-y0+6, S<-y0-2
    iter(y0 + 2, A0f, A0y, false, false, true);   // consume y0+5, S<-y0-1
    iter(y0 + 3, A1f, A1y, false, false, false);  // consume y0+6
}

extern "C" void kernel_launch(void* const* d_in, const int* in_sizes, int n_in,
                              void* d_out, int out_size, void* d_ws, size_t ws_size,
                              hipStream_t stream) {
    const float* inp = (const float*)d_in[0];
    const float* dep = (const float*)d_in[1];
    const float* alb = (const float*)d_in[2];
    const float* nrm = (const float*)d_in[3];
    float* out = (float*)d_out;
    dim3 grid((WW + OUTW - 1) / OUTW, HH / (RPB * WPB));   // 18 x 64, 256-thr blocks
    ls_sep_kernel<<<grid, dim3(WPB * 64), 0, stream>>>(inp, dep, alb, nrm, out);
}

// Round 10
// 124.452 us; speedup vs baseline: 1.9417x; 1.9417x over previous
//
#include <hip/hip_runtime.h>
#include <math.h>

#define HH 1024
#define WW 1024
#define OUTW 58            // output columns per wave (64 lanes - 6 halo)
#define RPB 4              // output rows per WAVE (vertical slide length)
#define WPB 4              // waves per block (independent y-strips, no barrier)
#define OFF(i) ((i)*8 - (i)*((i)-1)/2)   // packed upper-tri row offset

// ===== R26: re-rolled main body — shrink the I$ footprint =====
// Hard-won constraints (rounds 4..25):
//  - VGPR bucket MUST stay 128. WRITE_SIZE == 13536 KB is the no-spill
//    invariant (violations: r7/r16/r17/r18; R25 bpermute-tree: 299 MB,
//    172 us - compiler clusters 36 DS results in flight -> +30 live).
//  - Theories refuted: TLP up/down (r13/r10/R22/R23), VMEM latency
//    (R20 prefetch = -5%, now covered), block concurrency (R23),
//    solve-bubble ILP (R24), DS-pipe htap offload (R25).
//  - Counter calibration: VALUBusy counts execute-occupancy (2cy/inst);
//    VALUBusy x dur / 2cy ~= 750 VALU inst/iter = static count. Chip at
//    ~48%; per-wave VALU occupancy D ~= 0.36 -> 64% of wave cycles are
//    a stall source that is NOT data-side (loads covered, ILP high).
//  - Cross-lane ops (DPP) never inside divergent flow (r8).
//  - No LDS prefetch: s_waitcnt vmcnt(0) drains output stores (r15).
// R26 theory: I$ THRASH. R21 = straight-line ~36 KB (1000 inst/iter x4
//  + prologue) vs 32 KiB per-CU I$; every wave cold-fetches the whole
//  stream. Fix: R22's rolled yb+=2 body at RPB=4 (2 iters ~16 KB, warm
//  on 2nd trip and for subsequent blocks). Everything else R21 verbatim.
//  Hint: R22's rolled body improved per-row time 3.97->3.6 us even as
//  RPB=8 residency regressed the total.

// DPP move, bound_ctrl=1 (invalid lanes read 0)
template<int CTRL>
__device__ __forceinline__ float dpp0(float x) {
    return __int_as_float(
        __builtin_amdgcn_update_dpp(0, __float_as_int(x), CTRL, 0xf, 0xf, true));
}
// whole-wave shift right by 1 lane (crosses 16-lane row boundaries)
__device__ __forceinline__ float wshr1(float x) { return dpp0<0x138>(x); }

// fp32 reciprocal: v_rcp_f32 + 1 Newton step (~1ulp); LDL^T is sqrt-free
__device__ __forceinline__ float frcp_fast(float s) {
    float r = __builtin_amdgcn_rcpf(s);
    return r * fmaf(-s, r, 2.0f);
}

static_assert((RPB & 1) == 0, "double-iter rolled body needs even RPB");

__global__ __launch_bounds__(WPB * 64, 2) void ls_sep_kernel(
    const float* __restrict__ inp,    // [3,H,W]
    const float* __restrict__ dep,    // [1,H,W]
    const float* __restrict__ alb,    // [3,H,W]
    const float* __restrict__ nrm,    // [3,H,W]
    float* __restrict__ out)          // [3,H,W]
{
    const int L  = threadIdx.x & 63;          // lane 0..63
    const int wv = threadIdx.x >> 6;          // wave 0..3 (independent y-strip)
    const int HW = HH * WW;
    // lane L sums column x; its horizontal window (x-6..x) is centered at x-3
    const int x  = OUTW * blockIdx.x - 3 + L;
    const int y0 = (RPB * WPB) * blockIdx.y + RPB * wv;
    const int px = x - 3;                     // output pixel column for this lane

    const int xc    = min(max(x, 0), WW - 1);
    const float xok = (x >= 0 && x < WW) ? 1.f : 0.f;

    // per-channel SGPR base pointers (one s-pair each; loads share voffset)
    const float* __restrict__ d0 = dep;
    const float* __restrict__ a0 = alb;
    const float* __restrict__ a1 = alb + HW;
    const float* __restrict__ a2 = alb + 2 * HW;
    const float* __restrict__ n0 = nrm;
    const float* __restrict__ n1 = nrm + HW;
    const float* __restrict__ n2 = nrm + 2 * HW;
    const float* __restrict__ i0 = inp;
    const float* __restrict__ i1 = inp + HW;
    const float* __restrict__ i2 = inp + 2 * HW;
    float* __restrict__ o0 = out;
    float* __restrict__ o1 = out + HW;
    float* __restrict__ o2 = out + 2 * HW;

    float C[60];                              // running column sums (7 rows in y)
    #pragma unroll
    for (int k = 0; k < 60; k++) C[k] = 0.f;

    // clamped-address loads only; no C update (prefetchable)
    auto load_row = [&](int yy, float (&fv)[8], float (&yv)[3]) {
        const int yc = min(max(yy, 0), HH - 1);
        const int p = yc * WW + xc;
        fv[0] = 1.f;
        fv[1] = d0[p];
        fv[2] = a0[p];
        fv[3] = a1[p];
        fv[4] = a2[p];
        fv[5] = n0[p];
        fv[6] = n1[p];
        fv[7] = n2[p];
        yv[0] = i0[p];
        yv[1] = i1[p];
        yv[2] = i2[p];
    };

    // masked accumulate of a loaded row into the column sums
    auto apply_row = [&](const float (&fv)[8], const float (&yv)[3],
                         int yy, float sgn) {
        const float ok = (yy >= 0 && yy < HH) ? xok : 0.f;
        const float s = sgn * ok;
        float fs[8];
        #pragma unroll
        for (int i = 0; i < 8; i++) fs[i] = fv[i] * s;
        int k = 0;
        #pragma unroll
        for (int i = 0; i < 8; i++)
            #pragma unroll
            for (int j = i; j < 8; j++) { C[k] = fmaf(fs[i], fv[j], C[k]); k++; }
        #pragma unroll
        for (int i = 0; i < 8; i++)
            #pragma unroll
            for (int c = 0; c < 3; c++)
                C[36 + i * 3 + c] = fmaf(fs[i], yv[c], C[36 + i * 3 + c]);
    };

    // prologue: fill the depth-2 add-row pipeline
    float A0f[8], A0y[3], A1f[8], A1y[3];
    load_row(y0 + 3, A0f, A0y);
    load_row(y0 + 4, A1f, A1y);

    // preload rows y0-3 .. y0+2 (iter y0 skips the subtract)
    #pragma unroll 2
    for (int yy = y0 - 3; yy < y0 + 3; yy++) {
        float fv[8], yv[3];
        load_row(yy, fv, yv);
        apply_row(fv, yv, yy, 1.f);
    }

    float Sf[8], Sy[3];                       // sub-row buffer (depth 1)

    const int pxc = min(max(px, 0), WW - 1);
    const bool do_store = (L >= 6) && (px < WW);

    // Batched horizontal 7-tap over lanes L-6..L for 12 values at once.
    // 6-step fused-DPP prefix chain (v_add_f32_dpp, no DS ops).
    // MUST be called by all 64 lanes (cross-lane inside).
    auto htap12 = [&](int base, float* dst) {
        #pragma unroll
        for (int j = 0; j < 12; j++) {
            const float xv = C[base + j];
            float S = xv;
            #pragma unroll
            for (int t = 0; t < 6; t++) S = xv + wshr1(S);
            dst[j] = S;
        }
    };

    // one output row; Af/Ay is the add-row buffer holding row y+3.
    // loadA: refill Af with row y+5 (consumed 2 iters later).
    // loadS: refill Sf with row y-3 (consumed next iter).
    auto iter = [&](int y, float (&Af)[8], float (&Ay)[3],
                    bool first, bool loadA, bool loadS) {
        // ---- consume prefetched rows ----
        apply_row(Af, Ay, y + 3, 1.f);
        if (!first) apply_row(Sf, Sy, y - 4, -1.f);     // wave-uniform

        // ---- issue loads in consumption order: cf -> S -> A ----
        const int pc = y * WW + pxc;          // center features (this iter)
        float cf[8];
        cf[0] = 1.f;
        cf[1] = d0[pc];
        cf[2] = a0[pc]; cf[3] = a1[pc]; cf[4] = a2[pc];
        cf[5] = n0[pc]; cf[6] = n1[pc]; cf[7] = n2[pc];

        if (loadS) load_row(y - 3, Sf, Sy);   // next iter's sub-row
        if (loadA) load_row(y + 5, Af, Ay);   // iter+2's add-row

        // ---- horizontal taps for AtA (AtY deferred past the solve) ----
        float W[36];
        htap12(0,  &W[0]);
        htap12(12, &W[12]);
        htap12(24, &W[24]);
        #pragma unroll
        for (int i = 0; i < 8; i++) W[OFF(i)] += 1.0e-4f;

        // ---- fp32 LDL^T (sqrt-free). W row i keeps R_ij = d_i*U_ij ----
        float idv[8];
        #pragma unroll
        for (int i = 0; i < 8; i++) {
            #pragma unroll
            for (int k = 0; k < i; k++) {
                const float c = W[OFF(k) + i - k] * idv[k];   // U_ki
                #pragma unroll
                for (int j = i; j < 8; j++)
                    W[OFF(i) + j - i] = fmaf(-c, W[OFF(k) + j - k], W[OFF(i) + j - i]);
            }
            idv[i] = frcp_fast(W[OFF(i)]);    // 1/d_i
        }

        // forward: vt_i = idv_i * (cf_i - sum_{k<i} R_ki * vt_k)
        float vt[8];
        #pragma unroll
        for (int i = 0; i < 8; i++) {
            float s = cf[i];
            #pragma unroll
            for (int k = 0; k < i; k++)
                s = fmaf(-W[OFF(k) + i - k], vt[k], s);
            vt[i] = s * idv[i];
        }
        // back: w_i = vt_i - idv_i * sum_{j>i} R_ij * w_j
        float w[8];
        #pragma unroll
        for (int i = 7; i >= 0; i--) {
            float t = 0.f;
            #pragma unroll
            for (int j = i + 1; j < 8; j++)
                t = fmaf(W[OFF(i) + j - i], w[j], t);
            w[i] = fmaf(-idv[i], t, vt[i]);
        }

        // ---- deferred AtY taps (batched) + output dot products:
        //      ALL lanes execute; only the store is predicated ----
        float r[3] = {0.f, 0.f, 0.f};
        {
            float SY[12];
            htap12(36, SY);                   // AtY for i=0..3
            #pragma unroll
            for (int i = 0; i < 4; i++)
                #pragma unroll
                for (int c = 0; c < 3; c++)
                    r[c] = fmaf(w[i], SY[i * 3 + c], r[c]);
            htap12(48, SY);                   // AtY for i=4..7
            #pragma unroll
            for (int i = 0; i < 4; i++)
                #pragma unroll
                for (int c = 0; c < 3; c++)
                    r[c] = fmaf(w[i + 4], SY[i * 3 + c], r[c]);
        }

        if (do_store) {
            const int p = y * WW + px;
            o0[p] = r[0];
            o1[p] = r[1];
            o2[p] = r[2];
        }
    };

    // ROLLED double-iter body (I$ footprint ~halved vs full unroll).
    // Static A0/A1 ping-pong; flags are wave-uniform runtime branches.
    // Schedule == R21's static one:
    //  y0  : A0 own-add; A0<-y0+5; S<-y0-3
    //  y0+1: A1 own-add; A1<-y0+6; S<-y0-2
    //  y0+2: consume y0+5; S<-y0-1
    //  y0+3: consume y0+6; no loads
    #pragma unroll 1
    for (int yb = 0; yb < RPB; yb += 2) {
        const int y = y0 + yb;
        iter(y,     A0f, A0y, yb == 0, yb + 2 < RPB, true);
        iter(y + 1, A1f, A1y, false,   yb + 3 < RPB, yb + 2 < RPB);
    }
}

extern "C" void kernel_launch(void* const* d_in, const int* in_sizes, int n_in,
                              void* d_out, int out_size, void* d_ws, size_t ws_size,
                              hipStream_t stream) {
    const float* inp = (const float*)d_in[0];
    const float* dep = (const float*)d_in[1];
    const float* alb = (const float*)d_in[2];
    const float* nrm = (const float*)d_in[3];
    float* out = (float*)d_out;
    dim3 grid((WW + OUTW - 1) / OUTW, HH / (RPB * WPB));   // 18 x 64, 256-thr blocks
    ls_sep_kernel<<<grid, dim3(WPB * 64), 0, stream>>>(inp, dep, alb, nrm, out);
}